// Round 5
// baseline (962.965 us; speedup 1.0000x reference)
//
#include <hip/hip_runtime.h>
#include <hip/hip_bf16.h>

#define S_LEN 2048
#define D_DIM 128
#define H_NUM 16

typedef float f32x4 __attribute__((ext_vector_type(4)));
typedef _Float16 f16x8 __attribute__((ext_vector_type(8)));
typedef _Float16 f16x4 __attribute__((ext_vector_type(4)));

__device__ __forceinline__ _Float16 f2h(float f) { return (_Float16)f; }

// ---- convert weights fp32 -> fp16 once per call (L2-resident afterwards) ----
__global__ __launch_bounds__(256) void wconv_kernel(
    const float* __restrict__ Wq, const float* __restrict__ Wk,
    const float* __restrict__ Wv, _Float16* __restrict__ Wb) {
    int i = blockIdx.x * 256 + threadIdx.x;   // 16384 total
    Wb[i]         = f2h(Wq[i]);
    Wb[16384 + i] = f2h(Wk[i]);
    Wb[32768 + i] = f2h(Wv[i]);
}

// ---- fused QKV projection: y = x @ W^T + b ----
// Q,K: swapped operands mfma(W,x) -> lane holds 4 consecutive e -> f16x4 stores.
// V: mfma(x,W) -> lane holds 4 consecutive s -> f16x4 stores to V^T.
// grid: (BH=64) * (S/128=16) blocks, 256 threads (4 waves x 32 rows)
__global__ __launch_bounds__(256) void proj_kernel(
    const float* __restrict__ x,
    const float* __restrict__ bq, const float* __restrict__ bk,
    const float* __restrict__ bv,
    const _Float16* __restrict__ Wb,
    _Float16* __restrict__ Qg, _Float16* __restrict__ Kg, _Float16* __restrict__ Vt)
{
    const int blk = blockIdx.x;
    const int bh  = blk >> 4;
    const int st  = blk & 15;
    const int tid = threadIdx.x;
    const int w = tid >> 6, lane = tid & 63, g = lane >> 4, r16 = lane & 15;
    const int base = st * 128 + w * 32;

    // x fragments (serve as A- or B-operand: identical lane mapping)
    f16x8 xf[2][4];
    #pragma unroll
    for (int rs = 0; rs < 2; ++rs) {
        const int row = base + rs * 16 + r16;
        const float* xr = x + (size_t)(bh * S_LEN + row) * D_DIM + g * 8;
        #pragma unroll
        for (int kk = 0; kk < 4; ++kk) {
            float4 a = *(const float4*)(xr + kk * 32);
            float4 b = *(const float4*)(xr + kk * 32 + 4);
            f16x8 f;
            f[0]=f2h(a.x); f[1]=f2h(a.y); f[2]=f2h(a.z); f[3]=f2h(a.w);
            f[4]=f2h(b.x); f[5]=f2h(b.y); f[6]=f2h(b.z); f[7]=f2h(b.w);
            xf[rs][kk] = f;
        }
    }

    #pragma unroll 1
    for (int p = 0; p < 3; ++p) {
        const float* bias = (p == 0) ? bq : (p == 1) ? bk : bv;
        const _Float16* W = Wb + p * 16384;
        f32x4 acc[2][8];
        #pragma unroll
        for (int rs = 0; rs < 2; ++rs)
            #pragma unroll
            for (int et = 0; et < 8; ++et)
                acc[rs][et] = (f32x4){0.f, 0.f, 0.f, 0.f};

        #pragma unroll
        for (int et = 0; et < 8; ++et) {
            const _Float16* wr = W + (size_t)(et * 16 + r16) * 128 + g * 8;
            #pragma unroll
            for (int kk = 0; kk < 4; ++kk) {
                f16x8 wf = *(const f16x8*)(wr + kk * 32);
                if (p < 2) {  // swapped: C[row=e][col=s]
                    acc[0][et] = __builtin_amdgcn_mfma_f32_16x16x32_f16(wf, xf[0][kk], acc[0][et], 0, 0, 0);
                    acc[1][et] = __builtin_amdgcn_mfma_f32_16x16x32_f16(wf, xf[1][kk], acc[1][et], 0, 0, 0);
                } else {      // normal: C[row=s][col=e]
                    acc[0][et] = __builtin_amdgcn_mfma_f32_16x16x32_f16(xf[0][kk], wf, acc[0][et], 0, 0, 0);
                    acc[1][et] = __builtin_amdgcn_mfma_f32_16x16x32_f16(xf[1][kk], wf, acc[1][et], 0, 0, 0);
                }
            }
        }

        #pragma unroll
        for (int et = 0; et < 8; ++et) {
            #pragma unroll
            for (int rs = 0; rs < 2; ++rs) {
                if (p < 2) {
                    // col = r16 -> s ; row = g*4+i -> e (4 consecutive)
                    const int srow = base + rs * 16 + r16;
                    const int e0 = et * 16 + g * 4;
                    float4 b4 = *(const float4*)(bias + e0);
                    f16x4 o;
                    o[0] = f2h(acc[rs][et][0] + b4.x);
                    o[1] = f2h(acc[rs][et][1] + b4.y);
                    o[2] = f2h(acc[rs][et][2] + b4.z);
                    o[3] = f2h(acc[rs][et][3] + b4.w);
                    _Float16* O = (p == 0) ? Qg : Kg;
                    *(f16x4*)(O + (size_t)(bh * S_LEN + srow) * D_DIM + e0) = o;
                } else {
                    // col = r16 -> e ; row = g*4+i -> s (4 consecutive) -> V^T
                    const float be = bias[et * 16 + r16];
                    const int s0 = base + rs * 16 + g * 4;
                    f16x4 vv;
                    vv[0] = f2h(acc[rs][et][0] + be);
                    vv[1] = f2h(acc[rs][et][1] + be);
                    vv[2] = f2h(acc[rs][et][2] + be);
                    vv[3] = f2h(acc[rs][et][3] + be);
                    *(f16x4*)(Vt + (size_t)bh * D_DIM * S_LEN
                                 + (size_t)(et * 16 + r16) * S_LEN + s0) = vv;
                }
            }
        }
    }
}

// ---- flash attention: 128 q-rows/block (4 waves x QBLK=32), KV tile = 64 ----
// Swapped QK^T: S^T = mfma(K, Q) -> lane's S-values all belong to q-row r16.
// grid: BH*16 = 1024 blocks, 256 threads
__global__ __launch_bounds__(256) void attn_kernel(
    const _Float16* __restrict__ Qg, const _Float16* __restrict__ Kg,
    const _Float16* __restrict__ Vt, float* __restrict__ out)
{
    __shared__ _Float16 k_lds[64][136];    // 272B stride: uniform bank spread
    __shared__ _Float16 v_lds[128][72];    // 144B stride: uniform bank spread
    __shared__ _Float16 p_lds[4][32 * 64]; // per-wave P, XOR-swizzled

    const int blk = blockIdx.x;
    const int bh = blk >> 4;
    const int qt = blk & 15;
    const int b = bh >> 4, h = bh & 15;
    const int tid = threadIdx.x;
    const int w = tid >> 6, lane = tid & 63, g = lane >> 4, r16 = lane & 15;
    const int swz = (r16 & 7) << 3;

    // Q fragments: 2 sets x 4 k-steps (B-operand: col=r16 -> q-row)
    f16x8 qf[2][4];
    #pragma unroll
    for (int s = 0; s < 2; ++s) {
        const int qrow = qt * 128 + w * 32 + s * 16 + r16;
        const _Float16* qp = Qg + (size_t)(bh * S_LEN + qrow) * D_DIM + g * 8;
        #pragma unroll
        for (int kk = 0; kk < 4; ++kk) qf[s][kk] = *(const f16x8*)(qp + kk * 32);
    }

    f32x4 acc[2][8];
    #pragma unroll
    for (int s = 0; s < 2; ++s)
        #pragma unroll
        for (int dt = 0; dt < 8; ++dt) acc[s][dt] = (f32x4){0.f, 0.f, 0.f, 0.f};
    float m[2] = {-1e30f, -1e30f}, l[2] = {0.f, 0.f};

    const _Float16* Kb = Qg ? Kg + (size_t)bh * S_LEN * D_DIM : Kg;
    const _Float16* Vb = Vt + (size_t)bh * D_DIM * S_LEN;
    const float LOG2E = 1.4426950408889634f;

    // prologue: load tile 0 into regs
    uint4 kreg[4], vreg[4];
    #pragma unroll
    for (int cc = 0; cc < 4; ++cc) {
        const int off = (tid + cc * 256) * 8;
        kreg[cc] = *(const uint4*)(Kb + (size_t)(off >> 7) * D_DIM + (off & 127));
        vreg[cc] = *(const uint4*)(Vb + (size_t)(off >> 6) * S_LEN + (off & 63));
    }

    for (int kv = 0; kv < 32; ++kv) {
        __syncthreads();   // prev tile's LDS reads complete
        #pragma unroll
        for (int cc = 0; cc < 4; ++cc) {
            const int off = (tid + cc * 256) * 8;
            *(uint4*)&k_lds[off >> 7][off & 127] = kreg[cc];
            *(uint4*)&v_lds[off >> 6][off & 63] = vreg[cc];
        }
        __syncthreads();
        if (kv + 1 < 32) {  // issue next-tile loads; hide under compute (T14)
            #pragma unroll
            for (int cc = 0; cc < 4; ++cc) {
                const int off = (tid + cc * 256) * 8;
                kreg[cc] = *(const uint4*)(Kb + (size_t)((kv + 1) * 64 + (off >> 7)) * D_DIM + (off & 127));
                vreg[cc] = *(const uint4*)(Vb + (size_t)(off >> 6) * S_LEN + (kv + 1) * 64 + (off & 63));
            }
        }

        // S^T = K Q^T : C[row=key-local][col=q-local]
        f32x4 sacc[2][4];
        #pragma unroll
        for (int s = 0; s < 2; ++s)
            #pragma unroll
            for (int ct = 0; ct < 4; ++ct) sacc[s][ct] = (f32x4){0.f, 0.f, 0.f, 0.f};
        #pragma unroll
        for (int ct = 0; ct < 4; ++ct) {
            #pragma unroll
            for (int kk = 0; kk < 4; ++kk) {
                f16x8 kf = *(const f16x8*)&k_lds[ct * 16 + r16][kk * 32 + g * 8];
                sacc[0][ct] = __builtin_amdgcn_mfma_f32_16x16x32_f16(kf, qf[0][kk], sacc[0][ct], 0, 0, 0);
                sacc[1][ct] = __builtin_amdgcn_mfma_f32_16x16x32_f16(kf, qf[1][kk], sacc[1][ct], 0, 0, 0);
            }
        }

        // online softmax: lane owns q-row s*16+r16, keys {ct*16+g*4+i}
        #pragma unroll
        for (int s = 0; s < 2; ++s) {
            float t = sacc[s][0][0];
            #pragma unroll
            for (int ct = 0; ct < 4; ++ct)
                #pragma unroll
                for (int i = 0; i < 4; ++i) t = fmaxf(t, sacc[s][ct][i]);
            t = fmaxf(t, __shfl_xor(t, 16, 64));
            t = fmaxf(t, __shfl_xor(t, 32, 64));
            const float nm = fmaxf(m[s], t);
            const float al = exp2f((m[s] - nm) * LOG2E);
            m[s] = nm;

            float rsum = 0.f;
            _Float16* prow = &p_lds[w][(s * 16 + r16) * 64];
            #pragma unroll
            for (int ct = 0; ct < 4; ++ct) {
                f16x4 ph;
                #pragma unroll
                for (int i = 0; i < 4; ++i) {
                    const float pv = exp2f((sacc[s][ct][i] - nm) * LOG2E);
                    rsum += pv;
                    ph[i] = f2h(pv);
                }
                *(f16x4*)&prow[(ct * 16 + g * 4) ^ swz] = ph;
            }
            rsum += __shfl_xor(rsum, 16, 64);
            rsum += __shfl_xor(rsum, 32, 64);
            l[s] = l[s] * al + rsum;

            // rescale O: row q-local = g*4+i needs that row's alpha
            #pragma unroll
            for (int i = 0; i < 4; ++i) {
                const float ab = __shfl(al, g * 4 + i, 64);
                #pragma unroll
                for (int dt = 0; dt < 8; ++dt) acc[s][dt][i] *= ab;
            }
        }

        // O += P V : A=P (row=q-local=r16), B=V (col=d-local=r16)
        f16x8 pf[2][2];
        #pragma unroll
        for (int s = 0; s < 2; ++s)
            #pragma unroll
            for (int ks = 0; ks < 2; ++ks)
                pf[s][ks] = *(const f16x8*)&p_lds[w][(s * 16 + r16) * 64 + ((ks * 32 + g * 8) ^ swz)];
        #pragma unroll
        for (int ks = 0; ks < 2; ++ks) {
            #pragma unroll
            for (int dt = 0; dt < 8; ++dt) {
                f16x8 vf = *(const f16x8*)&v_lds[dt * 16 + r16][ks * 32 + g * 8];
                acc[0][dt] = __builtin_amdgcn_mfma_f32_16x16x32_f16(pf[0][ks], vf, acc[0][dt], 0, 0, 0);
                acc[1][dt] = __builtin_amdgcn_mfma_f32_16x16x32_f16(pf[1][ks], vf, acc[1][dt], 0, 0, 0);
            }
        }
    }

    // epilogue: out[b][s*H + h][d] = acc / l  (l lives in lane q=r16; shfl it)
    #pragma unroll
    for (int s = 0; s < 2; ++s) {
        #pragma unroll
        for (int i = 0; i < 4; ++i) {
            const float li = __shfl(l[s], g * 4 + i, 64);
            const float inv = 1.f / li;
            const int sg = qt * 128 + w * 32 + s * 16 + g * 4 + i;
            #pragma unroll
            for (int dt = 0; dt < 8; ++dt)
                out[(((size_t)b * S_LEN + sg) * H_NUM + h) * D_DIM + dt * 16 + r16]
                    = acc[s][dt][i] * inv;
        }
    }
}

extern "C" void kernel_launch(void* const* d_in, const int* in_sizes, int n_in,
                              void* d_out, int out_size, void* d_ws, size_t ws_size,
                              hipStream_t stream) {
    const float* x  = (const float*)d_in[0];
    const float* Wq = (const float*)d_in[1];
    const float* bq = (const float*)d_in[2];
    const float* Wk = (const float*)d_in[3];
    const float* bk = (const float*)d_in[4];
    const float* Wv = (const float*)d_in[5];
    const float* bv = (const float*)d_in[6];
    float* out = (float*)d_out;

    char* ws = (char*)d_ws;
    _Float16* Wb  = (_Float16*)ws;                     // 3*16384 f16 = 96 KB
    _Float16* Qg  = (_Float16*)(ws + 131072);          // 64*2048*128 f16 = 32 MB
    _Float16* Kg  = Qg + (size_t)64 * S_LEN * D_DIM;
    _Float16* Vtg = Kg + (size_t)64 * S_LEN * D_DIM;   // transposed V

    wconv_kernel<<<64, 256, 0, stream>>>(Wq, Wk, Wv, Wb);
    proj_kernel<<<1024, 256, 0, stream>>>(x, bq, bk, bv, Wb, Qg, Kg, Vtg);
    attn_kernel<<<1024, 256, 0, stream>>>(Qg, Kg, Vtg, out);
}

// Round 6
// 848.369 us; speedup vs baseline: 1.1351x; 1.1351x over previous
//
#include <hip/hip_runtime.h>
#include <hip/hip_bf16.h>

#define S_LEN 2048
#define D_DIM 128
#define H_NUM 16

typedef float f32x4 __attribute__((ext_vector_type(4)));
typedef _Float16 f16x8 __attribute__((ext_vector_type(8)));
typedef _Float16 f16x4 __attribute__((ext_vector_type(4)));

__device__ __forceinline__ _Float16 f2h(float f) { return (_Float16)f; }

// ---- convert weights fp32 -> fp16 once per call (L2-resident afterwards) ----
__global__ __launch_bounds__(256) void wconv_kernel(
    const float* __restrict__ Wq, const float* __restrict__ Wk,
    const float* __restrict__ Wv, _Float16* __restrict__ Wb) {
    int i = blockIdx.x * 256 + threadIdx.x;   // 16384 total
    Wb[i]         = f2h(Wq[i]);
    Wb[16384 + i] = f2h(Wk[i]);
    Wb[32768 + i] = f2h(Wv[i]);
}

// ---- fused QKV projection: y = x @ W^T + b ----
// Q,K: swapped operands mfma(W,x) -> lane holds 4 consecutive e -> f16x4 stores.
// V: mfma(x,W) -> lane holds 4 consecutive s -> f16x4 stores to V^T.
// grid: (BH=64) * (S/128=16) blocks, 256 threads (4 waves x 32 rows)
__global__ __launch_bounds__(256) void proj_kernel(
    const float* __restrict__ x,
    const float* __restrict__ bq, const float* __restrict__ bk,
    const float* __restrict__ bv,
    const _Float16* __restrict__ Wb,
    _Float16* __restrict__ Qg, _Float16* __restrict__ Kg, _Float16* __restrict__ Vt)
{
    const int blk = blockIdx.x;
    const int bh  = blk >> 4;
    const int st  = blk & 15;
    const int tid = threadIdx.x;
    const int w = tid >> 6, lane = tid & 63, g = lane >> 4, r16 = lane & 15;
    const int base = st * 128 + w * 32;

    // x fragments (serve as A- or B-operand: identical lane mapping)
    f16x8 xf[2][4];
    #pragma unroll
    for (int rs = 0; rs < 2; ++rs) {
        const int row = base + rs * 16 + r16;
        const float* xr = x + (size_t)(bh * S_LEN + row) * D_DIM + g * 8;
        #pragma unroll
        for (int kk = 0; kk < 4; ++kk) {
            float4 a = *(const float4*)(xr + kk * 32);
            float4 b = *(const float4*)(xr + kk * 32 + 4);
            f16x8 f;
            f[0]=f2h(a.x); f[1]=f2h(a.y); f[2]=f2h(a.z); f[3]=f2h(a.w);
            f[4]=f2h(b.x); f[5]=f2h(b.y); f[6]=f2h(b.z); f[7]=f2h(b.w);
            xf[rs][kk] = f;
        }
    }

    #pragma unroll 1
    for (int p = 0; p < 3; ++p) {
        const float* bias = (p == 0) ? bq : (p == 1) ? bk : bv;
        const _Float16* W = Wb + p * 16384;
        f32x4 acc[2][8];
        #pragma unroll
        for (int rs = 0; rs < 2; ++rs)
            #pragma unroll
            for (int et = 0; et < 8; ++et)
                acc[rs][et] = (f32x4){0.f, 0.f, 0.f, 0.f};

        #pragma unroll
        for (int et = 0; et < 8; ++et) {
            const _Float16* wr = W + (size_t)(et * 16 + r16) * 128 + g * 8;
            #pragma unroll
            for (int kk = 0; kk < 4; ++kk) {
                f16x8 wf = *(const f16x8*)(wr + kk * 32);
                if (p < 2) {  // swapped: C[row=e][col=s]
                    acc[0][et] = __builtin_amdgcn_mfma_f32_16x16x32_f16(wf, xf[0][kk], acc[0][et], 0, 0, 0);
                    acc[1][et] = __builtin_amdgcn_mfma_f32_16x16x32_f16(wf, xf[1][kk], acc[1][et], 0, 0, 0);
                } else {      // normal: C[row=s][col=e]
                    acc[0][et] = __builtin_amdgcn_mfma_f32_16x16x32_f16(xf[0][kk], wf, acc[0][et], 0, 0, 0);
                    acc[1][et] = __builtin_amdgcn_mfma_f32_16x16x32_f16(xf[1][kk], wf, acc[1][et], 0, 0, 0);
                }
            }
        }

        #pragma unroll
        for (int et = 0; et < 8; ++et) {
            #pragma unroll
            for (int rs = 0; rs < 2; ++rs) {
                if (p < 2) {
                    // col = r16 -> s ; row = g*4+i -> e (4 consecutive)
                    const int srow = base + rs * 16 + r16;
                    const int e0 = et * 16 + g * 4;
                    float4 b4 = *(const float4*)(bias + e0);
                    f16x4 o;
                    o[0] = f2h(acc[rs][et][0] + b4.x);
                    o[1] = f2h(acc[rs][et][1] + b4.y);
                    o[2] = f2h(acc[rs][et][2] + b4.z);
                    o[3] = f2h(acc[rs][et][3] + b4.w);
                    _Float16* O = (p == 0) ? Qg : Kg;
                    *(f16x4*)(O + (size_t)(bh * S_LEN + srow) * D_DIM + e0) = o;
                } else {
                    // col = r16 -> e ; row = g*4+i -> s (4 consecutive) -> V^T
                    const float be = bias[et * 16 + r16];
                    const int s0 = base + rs * 16 + g * 4;
                    f16x4 vv;
                    vv[0] = f2h(acc[rs][et][0] + be);
                    vv[1] = f2h(acc[rs][et][1] + be);
                    vv[2] = f2h(acc[rs][et][2] + be);
                    vv[3] = f2h(acc[rs][et][3] + be);
                    *(f16x4*)(Vt + (size_t)bh * D_DIM * S_LEN
                                 + (size_t)(et * 16 + r16) * S_LEN + s0) = vv;
                }
            }
        }
    }
}

// ---- flash attention: 64 q-rows/block (4 waves x 16), KV tile = 64 ----
// Swapped QK^T (mfma(K,Q)): lane r16 owns q-row r16 -> in-register softmax.
// Reg-staged prefetch of next K/V tile (T14). XCD-swizzled grid (2048%8==0).
// grid: BH*32 = 2048 blocks, 256 threads
__global__ __launch_bounds__(256, 3) void attn_kernel(
    const _Float16* __restrict__ Qg, const _Float16* __restrict__ Kg,
    const _Float16* __restrict__ Vt, float* __restrict__ out)
{
    __shared__ _Float16 k_lds[64][136];    // 272B row = 68dw ≡ 4 (mod 32): uniform quads
    __shared__ _Float16 v_lds[128][72];    // 144B row = 36dw ≡ 4 (mod 32): uniform quads
    __shared__ _Float16 p_lds[4][16][72];  // per-wave P; 16B-aligned rows, uniform

    const int wgid = ((blockIdx.x & 7) << 8) | (blockIdx.x >> 3);  // XCD swizzle
    const int bh = wgid >> 5;
    const int qt = wgid & 31;
    const int b = bh >> 4, h = bh & 15;
    const int tid = threadIdx.x;
    const int w = tid >> 6, lane = tid & 63, g = lane >> 4, r16 = lane & 15;

    // Q fragments (B-operand: col=r16 -> q-row qt*64 + w*16 + r16)
    f16x8 qf[4];
    {
        const int qrow = qt * 64 + w * 16 + r16;
        const _Float16* qp = Qg + (size_t)(bh * S_LEN + qrow) * D_DIM + g * 8;
        #pragma unroll
        for (int kk = 0; kk < 4; ++kk) qf[kk] = *(const f16x8*)(qp + kk * 32);
    }

    f32x4 acc[8];
    #pragma unroll
    for (int dt = 0; dt < 8; ++dt) acc[dt] = (f32x4){0.f, 0.f, 0.f, 0.f};
    float m = -1e30f, l = 0.f;

    const _Float16* Kb = Kg + (size_t)bh * S_LEN * D_DIM;
    const _Float16* Vb = Vt + (size_t)bh * D_DIM * S_LEN;
    const float LOG2E = 1.4426950408889634f;

    // prologue: tile 0 -> regs
    uint4 kreg[4], vreg[4];
    #pragma unroll
    for (int cc = 0; cc < 4; ++cc) {
        const int off = (tid + cc * 256) * 8;
        kreg[cc] = *(const uint4*)(Kb + (size_t)(off >> 7) * D_DIM + (off & 127));
        vreg[cc] = *(const uint4*)(Vb + (size_t)(off >> 6) * S_LEN + (off & 63));
    }

    for (int kv = 0; kv < 32; ++kv) {
        __syncthreads();   // prev tile's LDS reads complete
        #pragma unroll
        for (int cc = 0; cc < 4; ++cc) {
            const int off = (tid + cc * 256) * 8;
            *(uint4*)&k_lds[off >> 7][off & 127] = kreg[cc];
            *(uint4*)&v_lds[off >> 6][off & 63] = vreg[cc];
        }
        __syncthreads();
        if (kv + 1 < 32) {  // prefetch next tile; lands during compute (T14)
            #pragma unroll
            for (int cc = 0; cc < 4; ++cc) {
                const int off = (tid + cc * 256) * 8;
                kreg[cc] = *(const uint4*)(Kb + (size_t)((kv + 1) * 64 + (off >> 7)) * D_DIM + (off & 127));
                vreg[cc] = *(const uint4*)(Vb + (size_t)(off >> 6) * S_LEN + (kv + 1) * 64 + (off & 63));
            }
        }

        // S^T = K Q^T : sacc[ct][i] = S[key=ct*16+g*4+i][q=r16]
        f32x4 sacc[4];
        #pragma unroll
        for (int ct = 0; ct < 4; ++ct) sacc[ct] = (f32x4){0.f, 0.f, 0.f, 0.f};
        #pragma unroll
        for (int ct = 0; ct < 4; ++ct) {
            #pragma unroll
            for (int kk = 0; kk < 4; ++kk) {
                f16x8 kf = *(const f16x8*)&k_lds[ct * 16 + r16][kk * 32 + g * 8];
                sacc[ct] = __builtin_amdgcn_mfma_f32_16x16x32_f16(kf, qf[kk], sacc[ct], 0, 0, 0);
            }
        }

        // softmax: lane owns q-row r16 entirely (16 in-reg values, 2 shfls)
        float t0 = fmaxf(fmaxf(sacc[0][0], sacc[0][1]), fmaxf(sacc[0][2], sacc[0][3]));
        float t1 = fmaxf(fmaxf(sacc[1][0], sacc[1][1]), fmaxf(sacc[1][2], sacc[1][3]));
        float t2 = fmaxf(fmaxf(sacc[2][0], sacc[2][1]), fmaxf(sacc[2][2], sacc[2][3]));
        float t3 = fmaxf(fmaxf(sacc[3][0], sacc[3][1]), fmaxf(sacc[3][2], sacc[3][3]));
        float t = fmaxf(fmaxf(t0, t1), fmaxf(t2, t3));
        t = fmaxf(t, __shfl_xor(t, 16, 64));
        t = fmaxf(t, __shfl_xor(t, 32, 64));
        const float nm = fmaxf(m, t);
        const float al = exp2f((m - nm) * LOG2E);
        m = nm;

        float ex[4][4];
        #pragma unroll
        for (int ct = 0; ct < 4; ++ct) {
            f16x4 ph;
            #pragma unroll
            for (int i = 0; i < 4; ++i) {
                ex[ct][i] = exp2f((sacc[ct][i] - nm) * LOG2E);
                ph[i] = f2h(ex[ct][i]);
            }
            *(f16x4*)&p_lds[w][r16][ct * 16 + g * 4] = ph;
        }
        float r0 = (ex[0][0] + ex[0][1]) + (ex[0][2] + ex[0][3]);
        float r1 = (ex[1][0] + ex[1][1]) + (ex[1][2] + ex[1][3]);
        float r2 = (ex[2][0] + ex[2][1]) + (ex[2][2] + ex[2][3]);
        float r3 = (ex[3][0] + ex[3][1]) + (ex[3][2] + ex[3][3]);
        float rsum = (r0 + r1) + (r2 + r3);
        rsum += __shfl_xor(rsum, 16, 64);
        rsum += __shfl_xor(rsum, 32, 64);
        l = l * al + rsum;

        // rescale O: acc row q = g*4+i needs that row's alpha
        #pragma unroll
        for (int i = 0; i < 4; ++i) {
            const float ab = __shfl(al, g * 4 + i, 64);
            #pragma unroll
            for (int dt = 0; dt < 8; ++dt) acc[dt][i] *= ab;
        }

        // O += P V : A=P[q=r16][key], B=V^T (col=d=r16)
        f16x8 pf[2];
        #pragma unroll
        for (int ks = 0; ks < 2; ++ks)
            pf[ks] = *(const f16x8*)&p_lds[w][r16][ks * 32 + g * 8];
        #pragma unroll
        for (int ks = 0; ks < 2; ++ks) {
            #pragma unroll
            for (int dt = 0; dt < 8; ++dt) {
                f16x8 vf = *(const f16x8*)&v_lds[dt * 16 + r16][ks * 32 + g * 8];
                acc[dt] = __builtin_amdgcn_mfma_f32_16x16x32_f16(pf[ks], vf, acc[dt], 0, 0, 0);
            }
        }
    }

    // epilogue: out[b][s*H + h][d] = acc / l  (l lives in lane q=r16; shfl it)
    #pragma unroll
    for (int i = 0; i < 4; ++i) {
        const float li = __shfl(l, g * 4 + i, 64);
        const float inv = 1.f / li;
        const int sg = qt * 64 + w * 16 + g * 4 + i;
        #pragma unroll
        for (int dt = 0; dt < 8; ++dt)
            out[(((size_t)b * S_LEN + sg) * H_NUM + h) * D_DIM + dt * 16 + r16]
                = acc[dt][i] * inv;
    }
}

extern "C" void kernel_launch(void* const* d_in, const int* in_sizes, int n_in,
                              void* d_out, int out_size, void* d_ws, size_t ws_size,
                              hipStream_t stream) {
    const float* x  = (const float*)d_in[0];
    const float* Wq = (const float*)d_in[1];
    const float* bq = (const float*)d_in[2];
    const float* Wk = (const float*)d_in[3];
    const float* bk = (const float*)d_in[4];
    const float* Wv = (const float*)d_in[5];
    const float* bv = (const float*)d_in[6];
    float* out = (float*)d_out;

    char* ws = (char*)d_ws;
    _Float16* Wb  = (_Float16*)ws;                     // 3*16384 f16 = 96 KB
    _Float16* Qg  = (_Float16*)(ws + 131072);          // 64*2048*128 f16 = 32 MB
    _Float16* Kg  = Qg + (size_t)64 * S_LEN * D_DIM;
    _Float16* Vtg = Kg + (size_t)64 * S_LEN * D_DIM;   // transposed V

    wconv_kernel<<<64, 256, 0, stream>>>(Wq, Wk, Wv, Wb);
    proj_kernel<<<1024, 256, 0, stream>>>(x, bq, bk, bv, Wb, Qg, Kg, Vtg);
    attn_kernel<<<2048, 256, 0, stream>>>(Qg, Kg, Vtg, out);
}

// Round 8
// 781.918 us; speedup vs baseline: 1.2315x; 1.0850x over previous
//
#include <hip/hip_runtime.h>
#include <hip/hip_bf16.h>

#define S_LEN 2048
#define D_DIM 128
#define H_NUM 16

typedef float f32x4 __attribute__((ext_vector_type(4)));
typedef _Float16 f16x8 __attribute__((ext_vector_type(8)));
typedef _Float16 f16x4 __attribute__((ext_vector_type(4)));

__device__ __forceinline__ _Float16 f2h(float f) { return (_Float16)f; }

// ---- convert weights fp32 -> fp16 once per call (L2-resident afterwards) ----
__global__ __launch_bounds__(256) void wconv_kernel(
    const float* __restrict__ Wq, const float* __restrict__ Wk,
    const float* __restrict__ Wv, _Float16* __restrict__ Wb) {
    int i = blockIdx.x * 256 + threadIdx.x;   // 16384 total
    Wb[i]         = f2h(Wq[i]);
    Wb[16384 + i] = f2h(Wk[i]);
    Wb[32768 + i] = f2h(Wv[i]);
}

// ---- fused QKV projection: y = x @ W^T + b ----
// Q,K: swapped operands mfma(W,x) -> lane holds 4 consecutive e -> f16x4 stores.
// V: mfma(x,W) -> lane holds 4 consecutive s -> f16x4 stores to V^T.
// grid: (BH=64) * (S/128=16) blocks, 256 threads (4 waves x 32 rows)
__global__ __launch_bounds__(256) void proj_kernel(
    const float* __restrict__ x,
    const float* __restrict__ bq, const float* __restrict__ bk,
    const float* __restrict__ bv,
    const _Float16* __restrict__ Wb,
    _Float16* __restrict__ Qg, _Float16* __restrict__ Kg, _Float16* __restrict__ Vt)
{
    const int blk = blockIdx.x;
    const int bh  = blk >> 4;
    const int st  = blk & 15;
    const int tid = threadIdx.x;
    const int w = tid >> 6, lane = tid & 63, g = lane >> 4, r16 = lane & 15;
    const int base = st * 128 + w * 32;

    // x fragments (serve as A- or B-operand: identical lane mapping)
    f16x8 xf[2][4];
    #pragma unroll
    for (int rs = 0; rs < 2; ++rs) {
        const int row = base + rs * 16 + r16;
        const float* xr = x + (size_t)(bh * S_LEN + row) * D_DIM + g * 8;
        #pragma unroll
        for (int kk = 0; kk < 4; ++kk) {
            float4 a = *(const float4*)(xr + kk * 32);
            float4 b = *(const float4*)(xr + kk * 32 + 4);
            f16x8 f;
            f[0]=f2h(a.x); f[1]=f2h(a.y); f[2]=f2h(a.z); f[3]=f2h(a.w);
            f[4]=f2h(b.x); f[5]=f2h(b.y); f[6]=f2h(b.z); f[7]=f2h(b.w);
            xf[rs][kk] = f;
        }
    }

    #pragma unroll 1
    for (int p = 0; p < 3; ++p) {
        const float* bias = (p == 0) ? bq : (p == 1) ? bk : bv;
        const _Float16* W = Wb + p * 16384;
        f32x4 acc[2][8];
        #pragma unroll
        for (int rs = 0; rs < 2; ++rs)
            #pragma unroll
            for (int et = 0; et < 8; ++et)
                acc[rs][et] = (f32x4){0.f, 0.f, 0.f, 0.f};

        #pragma unroll
        for (int et = 0; et < 8; ++et) {
            const _Float16* wr = W + (size_t)(et * 16 + r16) * 128 + g * 8;
            #pragma unroll
            for (int kk = 0; kk < 4; ++kk) {
                f16x8 wf = *(const f16x8*)(wr + kk * 32);
                if (p < 2) {  // swapped: C[row=e][col=s]
                    acc[0][et] = __builtin_amdgcn_mfma_f32_16x16x32_f16(wf, xf[0][kk], acc[0][et], 0, 0, 0);
                    acc[1][et] = __builtin_amdgcn_mfma_f32_16x16x32_f16(wf, xf[1][kk], acc[1][et], 0, 0, 0);
                } else {      // normal: C[row=s][col=e]
                    acc[0][et] = __builtin_amdgcn_mfma_f32_16x16x32_f16(xf[0][kk], wf, acc[0][et], 0, 0, 0);
                    acc[1][et] = __builtin_amdgcn_mfma_f32_16x16x32_f16(xf[1][kk], wf, acc[1][et], 0, 0, 0);
                }
            }
        }

        #pragma unroll
        for (int et = 0; et < 8; ++et) {
            #pragma unroll
            for (int rs = 0; rs < 2; ++rs) {
                if (p < 2) {
                    // col = r16 -> s ; row = g*4+i -> e (4 consecutive)
                    const int srow = base + rs * 16 + r16;
                    const int e0 = et * 16 + g * 4;
                    float4 b4 = *(const float4*)(bias + e0);
                    f16x4 o;
                    o[0] = f2h(acc[rs][et][0] + b4.x);
                    o[1] = f2h(acc[rs][et][1] + b4.y);
                    o[2] = f2h(acc[rs][et][2] + b4.z);
                    o[3] = f2h(acc[rs][et][3] + b4.w);
                    _Float16* O = (p == 0) ? Qg : Kg;
                    *(f16x4*)(O + (size_t)(bh * S_LEN + srow) * D_DIM + e0) = o;
                } else {
                    // col = r16 -> e ; row = g*4+i -> s (4 consecutive) -> V^T
                    const float be = bias[et * 16 + r16];
                    const int s0 = base + rs * 16 + g * 4;
                    f16x4 vv;
                    vv[0] = f2h(acc[rs][et][0] + be);
                    vv[1] = f2h(acc[rs][et][1] + be);
                    vv[2] = f2h(acc[rs][et][2] + be);
                    vv[3] = f2h(acc[rs][et][3] + be);
                    *(f16x4*)(Vt + (size_t)bh * D_DIM * S_LEN
                                 + (size_t)(et * 16 + r16) * S_LEN + s0) = vv;
                }
            }
        }
    }
}

// ---- flash attention: 64 q-rows/block (4 waves x 16), KV tile = 64 ----
// Swapped QK^T (mfma(K,Q)): lane r16 owns q-row r16 -> in-register softmax.
// Reg-staged prefetch of next K/V tile (T14); NO launch_bounds min-wave hint
// (the ",3" hint made the allocator spill the prefetch regs -> 1.9 GB scratch).
// T13 defer-max: skip rescale when tile max doesn't raise running max by >8.
// grid: BH*32 = 2048 blocks, 256 threads, XCD-swizzled (2048%8==0)
__global__ __launch_bounds__(256) void attn_kernel(
    const _Float16* __restrict__ Qg, const _Float16* __restrict__ Kg,
    const _Float16* __restrict__ Vt, float* __restrict__ out)
{
    __shared__ _Float16 k_lds[64][136];    // 272B row = 68dw ≡ 4 (mod 32): uniform quads
    __shared__ _Float16 v_lds[128][72];    // 144B row = 36dw ≡ 4 (mod 32): uniform quads
    __shared__ _Float16 p_lds[4][16][72];  // per-wave P; 16B-aligned rows, uniform

    const int wgid = ((blockIdx.x & 7) << 8) | (blockIdx.x >> 3);  // XCD swizzle
    const int bh = wgid >> 5;
    const int qt = wgid & 31;
    const int b = bh >> 4, h = bh & 15;
    const int tid = threadIdx.x;
    const int w = tid >> 6, lane = tid & 63, g = lane >> 4, r16 = lane & 15;

    // Q fragments (B-operand: col=r16 -> q-row qt*64 + w*16 + r16)
    f16x8 qf[4];
    {
        const int qrow = qt * 64 + w * 16 + r16;
        const _Float16* qp = Qg + (size_t)(bh * S_LEN + qrow) * D_DIM + g * 8;
        #pragma unroll
        for (int kk = 0; kk < 4; ++kk) qf[kk] = *(const f16x8*)(qp + kk * 32);
    }

    f32x4 acc[8];
    #pragma unroll
    for (int dt = 0; dt < 8; ++dt) acc[dt] = (f32x4){0.f, 0.f, 0.f, 0.f};
    float m = -1e30f, l = 0.f;

    const _Float16* Kb = Kg + (size_t)bh * S_LEN * D_DIM;
    const _Float16* Vb = Vt + (size_t)bh * D_DIM * S_LEN;
    const float LOG2E = 1.4426950408889634f;

    // prologue: tile 0 -> regs
    uint4 kreg[4], vreg[4];
    #pragma unroll
    for (int cc = 0; cc < 4; ++cc) {
        const int off = (tid + cc * 256) * 8;
        kreg[cc] = *(const uint4*)(Kb + (size_t)(off >> 7) * D_DIM + (off & 127));
        vreg[cc] = *(const uint4*)(Vb + (size_t)(off >> 6) * S_LEN + (off & 63));
    }

    for (int kv = 0; kv < 32; ++kv) {
        __syncthreads();   // prev tile's LDS reads complete
        #pragma unroll
        for (int cc = 0; cc < 4; ++cc) {
            const int off = (tid + cc * 256) * 8;
            *(uint4*)&k_lds[off >> 7][off & 127] = kreg[cc];
            *(uint4*)&v_lds[off >> 6][off & 63] = vreg[cc];
        }
        __syncthreads();
        if (kv + 1 < 32) {  // prefetch next tile; lands during compute (T14)
            #pragma unroll
            for (int cc = 0; cc < 4; ++cc) {
                const int off = (tid + cc * 256) * 8;
                kreg[cc] = *(const uint4*)(Kb + (size_t)((kv + 1) * 64 + (off >> 7)) * D_DIM + (off & 127));
                vreg[cc] = *(const uint4*)(Vb + (size_t)(off >> 6) * S_LEN + (kv + 1) * 64 + (off & 63));
            }
        }

        // S^T = K Q^T : sacc[ct][i] = S[key=ct*16+g*4+i][q=r16]
        f32x4 sacc[4];
        #pragma unroll
        for (int ct = 0; ct < 4; ++ct) sacc[ct] = (f32x4){0.f, 0.f, 0.f, 0.f};
        #pragma unroll
        for (int ct = 0; ct < 4; ++ct) {
            #pragma unroll
            for (int kk = 0; kk < 4; ++kk) {
                f16x8 kf = *(const f16x8*)&k_lds[ct * 16 + r16][kk * 32 + g * 8];
                sacc[ct] = __builtin_amdgcn_mfma_f32_16x16x32_f16(kf, qf[kk], sacc[ct], 0, 0, 0);
            }
        }

        // softmax: lane owns q-row r16 entirely (16 in-reg values, 2 shfls)
        float t0 = fmaxf(fmaxf(sacc[0][0], sacc[0][1]), fmaxf(sacc[0][2], sacc[0][3]));
        float t1 = fmaxf(fmaxf(sacc[1][0], sacc[1][1]), fmaxf(sacc[1][2], sacc[1][3]));
        float t2 = fmaxf(fmaxf(sacc[2][0], sacc[2][1]), fmaxf(sacc[2][2], sacc[2][3]));
        float t3 = fmaxf(fmaxf(sacc[3][0], sacc[3][1]), fmaxf(sacc[3][2], sacc[3][3]));
        float t = fmaxf(fmaxf(t0, t1), fmaxf(t2, t3));
        t = fmaxf(t, __shfl_xor(t, 16, 64));
        t = fmaxf(t, __shfl_xor(t, 32, 64));

        // T13 defer-max: only rescale when the max actually moves by >8
        float nm = m, al = 1.f;
        const bool need = !__all(t <= m + 8.f);
        if (need) {
            nm = fmaxf(m, t);
            al = exp2f((m - nm) * LOG2E);
            m = nm;
        }

        float ex[4][4];
        #pragma unroll
        for (int ct = 0; ct < 4; ++ct) {
            f16x4 ph;
            #pragma unroll
            for (int i = 0; i < 4; ++i) {
                ex[ct][i] = exp2f((sacc[ct][i] - nm) * LOG2E);
                ph[i] = f2h(ex[ct][i]);
            }
            *(f16x4*)&p_lds[w][r16][ct * 16 + g * 4] = ph;
        }
        float r0 = (ex[0][0] + ex[0][1]) + (ex[0][2] + ex[0][3]);
        float r1 = (ex[1][0] + ex[1][1]) + (ex[1][2] + ex[1][3]);
        float r2 = (ex[2][0] + ex[2][1]) + (ex[2][2] + ex[2][3]);
        float r3 = (ex[3][0] + ex[3][1]) + (ex[3][2] + ex[3][3]);
        float rsum = (r0 + r1) + (r2 + r3);
        rsum += __shfl_xor(rsum, 16, 64);
        rsum += __shfl_xor(rsum, 32, 64);
        l = l * al + rsum;

        if (need) {
            // rescale O: acc row q = g*4+i needs that row's alpha
            #pragma unroll
            for (int i = 0; i < 4; ++i) {
                const float ab = __shfl(al, g * 4 + i, 64);
                #pragma unroll
                for (int dt = 0; dt < 8; ++dt) acc[dt][i] *= ab;
            }
        }

        // O += P V : A=P[q=r16][key], B=V^T (col=d=r16)
        f16x8 pf[2];
        #pragma unroll
        for (int ks = 0; ks < 2; ++ks)
            pf[ks] = *(const f16x8*)&p_lds[w][r16][ks * 32 + g * 8];
        #pragma unroll
        for (int ks = 0; ks < 2; ++ks) {
            #pragma unroll
            for (int dt = 0; dt < 8; ++dt) {
                f16x8 vf = *(const f16x8*)&v_lds[dt * 16 + r16][ks * 32 + g * 8];
                acc[dt] = __builtin_amdgcn_mfma_f32_16x16x32_f16(pf[ks], vf, acc[dt], 0, 0, 0);
            }
        }
    }

    // epilogue: out[b][s*H + h][d] = acc / l  (l lives in lane q=r16; shfl it)
    #pragma unroll
    for (int i = 0; i < 4; ++i) {
        const float li = __shfl(l, g * 4 + i, 64);
        const float inv = 1.f / li;
        const int sg = qt * 64 + w * 16 + g * 4 + i;
        #pragma unroll
        for (int dt = 0; dt < 8; ++dt)
            out[(((size_t)b * S_LEN + sg) * H_NUM + h) * D_DIM + dt * 16 + r16]
                = acc[dt][i] * inv;
    }
}

extern "C" void kernel_launch(void* const* d_in, const int* in_sizes, int n_in,
                              void* d_out, int out_size, void* d_ws, size_t ws_size,
                              hipStream_t stream) {
    const float* x  = (const float*)d_in[0];
    const float* Wq = (const float*)d_in[1];
    const float* bq = (const float*)d_in[2];
    const float* Wk = (const float*)d_in[3];
    const float* bk = (const float*)d_in[4];
    const float* Wv = (const float*)d_in[5];
    const float* bv = (const float*)d_in[6];
    float* out = (float*)d_out;

    char* ws = (char*)d_ws;
    _Float16* Wb  = (_Float16*)ws;                     // 3*16384 f16 = 96 KB
    _Float16* Qg  = (_Float16*)(ws + 131072);          // 64*2048*128 f16 = 32 MB
    _Float16* Kg  = Qg + (size_t)64 * S_LEN * D_DIM;
    _Float16* Vtg = Kg + (size_t)64 * S_LEN * D_DIM;   // transposed V

    wconv_kernel<<<64, 256, 0, stream>>>(Wq, Wk, Wv, Wb);
    proj_kernel<<<1024, 256, 0, stream>>>(x, bq, bk, bv, Wb, Qg, Kg, Vtg);
    attn_kernel<<<2048, 256, 0, stream>>>(Qg, Kg, Vtg, out);
}

// Round 10
// 778.066 us; speedup vs baseline: 1.2376x; 1.0050x over previous
//
#include <hip/hip_runtime.h>
#include <hip/hip_bf16.h>

#define S_LEN 2048
#define D_DIM 128
#define H_NUM 16

typedef float f32x4 __attribute__((ext_vector_type(4)));
typedef _Float16 f16x8 __attribute__((ext_vector_type(8)));
typedef _Float16 f16x4 __attribute__((ext_vector_type(4)));

__device__ __forceinline__ _Float16 f2h(float f) { return (_Float16)f; }

// ---- convert weights fp32 -> fp16 once per call (L2-resident afterwards) ----
__global__ __launch_bounds__(256) void wconv_kernel(
    const float* __restrict__ Wq, const float* __restrict__ Wk,
    const float* __restrict__ Wv, _Float16* __restrict__ Wb) {
    int i = blockIdx.x * 256 + threadIdx.x;   // 16384 total
    Wb[i]         = f2h(Wq[i]);
    Wb[16384 + i] = f2h(Wk[i]);
    Wb[32768 + i] = f2h(Wv[i]);
}

// ---- fused QKV projection: y = x @ W^T + b ----
// Q,K: swapped operands mfma(W,x) -> lane holds 4 consecutive e -> f16x4 stores.
// V: mfma(x,W) -> lane holds 4 consecutive s -> f16x4 stores to V^T.
// grid: (BH=64) * (S/128=16) blocks, 256 threads (4 waves x 32 rows)
__global__ __launch_bounds__(256) void proj_kernel(
    const float* __restrict__ x,
    const float* __restrict__ bq, const float* __restrict__ bk,
    const float* __restrict__ bv,
    const _Float16* __restrict__ Wb,
    _Float16* __restrict__ Qg, _Float16* __restrict__ Kg, _Float16* __restrict__ Vt)
{
    const int blk = blockIdx.x;
    const int bh  = blk >> 4;
    const int st  = blk & 15;
    const int tid = threadIdx.x;
    const int w = tid >> 6, lane = tid & 63, g = lane >> 4, r16 = lane & 15;
    const int base = st * 128 + w * 32;

    // x fragments (serve as A- or B-operand: identical lane mapping)
    f16x8 xf[2][4];
    #pragma unroll
    for (int rs = 0; rs < 2; ++rs) {
        const int row = base + rs * 16 + r16;
        const float* xr = x + (size_t)(bh * S_LEN + row) * D_DIM + g * 8;
        #pragma unroll
        for (int kk = 0; kk < 4; ++kk) {
            float4 a = *(const float4*)(xr + kk * 32);
            float4 b = *(const float4*)(xr + kk * 32 + 4);
            f16x8 f;
            f[0]=f2h(a.x); f[1]=f2h(a.y); f[2]=f2h(a.z); f[3]=f2h(a.w);
            f[4]=f2h(b.x); f[5]=f2h(b.y); f[6]=f2h(b.z); f[7]=f2h(b.w);
            xf[rs][kk] = f;
        }
    }

    #pragma unroll 1
    for (int p = 0; p < 3; ++p) {
        const float* bias = (p == 0) ? bq : (p == 1) ? bk : bv;
        const _Float16* W = Wb + p * 16384;
        f32x4 acc[2][8];
        #pragma unroll
        for (int rs = 0; rs < 2; ++rs)
            #pragma unroll
            for (int et = 0; et < 8; ++et)
                acc[rs][et] = (f32x4){0.f, 0.f, 0.f, 0.f};

        #pragma unroll
        for (int et = 0; et < 8; ++et) {
            const _Float16* wr = W + (size_t)(et * 16 + r16) * 128 + g * 8;
            #pragma unroll
            for (int kk = 0; kk < 4; ++kk) {
                f16x8 wf = *(const f16x8*)(wr + kk * 32);
                if (p < 2) {  // swapped: C[row=e][col=s]
                    acc[0][et] = __builtin_amdgcn_mfma_f32_16x16x32_f16(wf, xf[0][kk], acc[0][et], 0, 0, 0);
                    acc[1][et] = __builtin_amdgcn_mfma_f32_16x16x32_f16(wf, xf[1][kk], acc[1][et], 0, 0, 0);
                } else {      // normal: C[row=s][col=e]
                    acc[0][et] = __builtin_amdgcn_mfma_f32_16x16x32_f16(xf[0][kk], wf, acc[0][et], 0, 0, 0);
                    acc[1][et] = __builtin_amdgcn_mfma_f32_16x16x32_f16(xf[1][kk], wf, acc[1][et], 0, 0, 0);
                }
            }
        }

        #pragma unroll
        for (int et = 0; et < 8; ++et) {
            #pragma unroll
            for (int rs = 0; rs < 2; ++rs) {
                if (p < 2) {
                    // col = r16 -> s ; row = g*4+i -> e (4 consecutive)
                    const int srow = base + rs * 16 + r16;
                    const int e0 = et * 16 + g * 4;
                    float4 b4 = *(const float4*)(bias + e0);
                    f16x4 o;
                    o[0] = f2h(acc[rs][et][0] + b4.x);
                    o[1] = f2h(acc[rs][et][1] + b4.y);
                    o[2] = f2h(acc[rs][et][2] + b4.z);
                    o[3] = f2h(acc[rs][et][3] + b4.w);
                    _Float16* O = (p == 0) ? Qg : Kg;
                    *(f16x4*)(O + (size_t)(bh * S_LEN + srow) * D_DIM + e0) = o;
                } else {
                    // col = r16 -> e ; row = g*4+i -> s (4 consecutive) -> V^T
                    const float be = bias[et * 16 + r16];
                    const int s0 = base + rs * 16 + g * 4;
                    f16x4 vv;
                    vv[0] = f2h(acc[rs][et][0] + be);
                    vv[1] = f2h(acc[rs][et][1] + be);
                    vv[2] = f2h(acc[rs][et][2] + be);
                    vv[3] = f2h(acc[rs][et][3] + be);
                    *(f16x4*)(Vt + (size_t)bh * D_DIM * S_LEN
                                 + (size_t)(et * 16 + r16) * S_LEN + s0) = vv;
                }
            }
        }
    }
}

// ---- flash attention: 64 q-rows/block (4 waves x 16), KV tile = 64 ----
// Swapped QK^T (mfma(K,Q)): lane r16 owns q-row r16 -> in-register softmax.
// Reg-staged prefetch of next K/V tile (T14).
// __launch_bounds__(256, 1): min-waves hint raised the VGPR cap to 512 —
//   default (no hint) targeted ~5 waves/EU -> 100-VGPR cap -> prefetch regs
//   spilled to scratch (711 MB of WRITE_SIZE). LDS (45 KB -> 3 blocks/CU)
//   is the intended occupancy limiter, not VGPR.
// T13 defer-max: skip rescale when tile max doesn't raise running max by >8.
// grid: BH*32 = 2048 blocks, 256 threads, XCD-swizzled (2048%8==0)
__global__ __launch_bounds__(256, 1) void attn_kernel(
    const _Float16* __restrict__ Qg, const _Float16* __restrict__ Kg,
    const _Float16* __restrict__ Vt, float* __restrict__ out)
{
    __shared__ _Float16 k_lds[64][136];    // 272B row: octet quad-slots distinct on read
    __shared__ _Float16 v_lds[128][72];    // 144B row: octet quad-slots distinct on read
    __shared__ _Float16 p_lds[4][16][72];  // per-wave P; 16B-aligned rows

    const int wgid = ((blockIdx.x & 7) << 8) | (blockIdx.x >> 3);  // XCD swizzle
    const int bh = wgid >> 5;
    const int qt = wgid & 31;
    const int b = bh >> 4, h = bh & 15;
    const int tid = threadIdx.x;
    const int w = tid >> 6, lane = tid & 63, g = lane >> 4, r16 = lane & 15;

    // Q fragments (B-operand: col=r16 -> q-row qt*64 + w*16 + r16)
    f16x8 qf[4];
    {
        const int qrow = qt * 64 + w * 16 + r16;
        const _Float16* qp = Qg + (size_t)(bh * S_LEN + qrow) * D_DIM + g * 8;
        #pragma unroll
        for (int kk = 0; kk < 4; ++kk) qf[kk] = *(const f16x8*)(qp + kk * 32);
    }

    f32x4 acc[8];
    #pragma unroll
    for (int dt = 0; dt < 8; ++dt) acc[dt] = (f32x4){0.f, 0.f, 0.f, 0.f};
    float m = -1e30f, l = 0.f;

    const _Float16* Kb = Kg + (size_t)bh * S_LEN * D_DIM;
    const _Float16* Vb = Vt + (size_t)bh * D_DIM * S_LEN;
    const float LOG2E = 1.4426950408889634f;

    // prologue: tile 0 -> regs
    uint4 kreg[4], vreg[4];
    #pragma unroll
    for (int cc = 0; cc < 4; ++cc) {
        const int off = (tid + cc * 256) * 8;
        kreg[cc] = *(const uint4*)(Kb + (size_t)(off >> 7) * D_DIM + (off & 127));
        vreg[cc] = *(const uint4*)(Vb + (size_t)(off >> 6) * S_LEN + (off & 63));
    }

    for (int kv = 0; kv < 32; ++kv) {
        __syncthreads();   // prev tile's LDS reads complete
        #pragma unroll
        for (int cc = 0; cc < 4; ++cc) {
            const int off = (tid + cc * 256) * 8;
            *(uint4*)&k_lds[off >> 7][off & 127] = kreg[cc];
            *(uint4*)&v_lds[off >> 6][off & 63] = vreg[cc];
        }
        __syncthreads();
        if (kv + 1 < 32) {  // prefetch next tile; lands during compute (T14)
            #pragma unroll
            for (int cc = 0; cc < 4; ++cc) {
                const int off = (tid + cc * 256) * 8;
                kreg[cc] = *(const uint4*)(Kb + (size_t)((kv + 1) * 64 + (off >> 7)) * D_DIM + (off & 127));
                vreg[cc] = *(const uint4*)(Vb + (size_t)(off >> 6) * S_LEN + (kv + 1) * 64 + (off & 63));
            }
        }

        // S^T = K Q^T : sacc[ct][i] = S[key=ct*16+g*4+i][q=r16]
        f32x4 sacc[4];
        #pragma unroll
        for (int ct = 0; ct < 4; ++ct) sacc[ct] = (f32x4){0.f, 0.f, 0.f, 0.f};
        #pragma unroll
        for (int ct = 0; ct < 4; ++ct) {
            #pragma unroll
            for (int kk = 0; kk < 4; ++kk) {
                f16x8 kf = *(const f16x8*)&k_lds[ct * 16 + r16][kk * 32 + g * 8];
                sacc[ct] = __builtin_amdgcn_mfma_f32_16x16x32_f16(kf, qf[kk], sacc[ct], 0, 0, 0);
            }
        }

        // softmax: lane owns q-row r16 entirely (16 in-reg values, 2 shfls)
        float t0 = fmaxf(fmaxf(sacc[0][0], sacc[0][1]), fmaxf(sacc[0][2], sacc[0][3]));
        float t1 = fmaxf(fmaxf(sacc[1][0], sacc[1][1]), fmaxf(sacc[1][2], sacc[1][3]));
        float t2 = fmaxf(fmaxf(sacc[2][0], sacc[2][1]), fmaxf(sacc[2][2], sacc[2][3]));
        float t3 = fmaxf(fmaxf(sacc[3][0], sacc[3][1]), fmaxf(sacc[3][2], sacc[3][3]));
        float t = fmaxf(fmaxf(t0, t1), fmaxf(t2, t3));
        t = fmaxf(t, __shfl_xor(t, 16, 64));
        t = fmaxf(t, __shfl_xor(t, 32, 64));

        // T13 defer-max: only rescale when the max actually moves by >8
        float nm = m, al = 1.f;
        const bool need = !__all(t <= m + 8.f);
        if (need) {
            nm = fmaxf(m, t);
            al = exp2f((m - nm) * LOG2E);
            m = nm;
        }

        float ex[4][4];
        #pragma unroll
        for (int ct = 0; ct < 4; ++ct) {
            f16x4 ph;
            #pragma unroll
            for (int i = 0; i < 4; ++i) {
                ex[ct][i] = exp2f((sacc[ct][i] - nm) * LOG2E);
                ph[i] = f2h(ex[ct][i]);
            }
            *(f16x4*)&p_lds[w][r16][ct * 16 + g * 4] = ph;
        }
        float r0 = (ex[0][0] + ex[0][1]) + (ex[0][2] + ex[0][3]);
        float r1 = (ex[1][0] + ex[1][1]) + (ex[1][2] + ex[1][3]);
        float r2 = (ex[2][0] + ex[2][1]) + (ex[2][2] + ex[2][3]);
        float r3 = (ex[3][0] + ex[3][1]) + (ex[3][2] + ex[3][3]);
        float rsum = (r0 + r1) + (r2 + r3);
        rsum += __shfl_xor(rsum, 16, 64);
        rsum += __shfl_xor(rsum, 32, 64);
        l = l * al + rsum;

        if (need) {
            // rescale O: acc row q = g*4+i needs that row's alpha
            #pragma unroll
            for (int i = 0; i < 4; ++i) {
                const float ab = __shfl(al, g * 4 + i, 64);
                #pragma unroll
                for (int dt = 0; dt < 8; ++dt) acc[dt][i] *= ab;
            }
        }

        // O += P V : A=P[q=r16][key], B=V^T (col=d=r16)
        f16x8 pf[2];
        #pragma unroll
        for (int ks = 0; ks < 2; ++ks)
            pf[ks] = *(const f16x8*)&p_lds[w][r16][ks * 32 + g * 8];
        #pragma unroll
        for (int ks = 0; ks < 2; ++ks) {
            #pragma unroll
            for (int dt = 0; dt < 8; ++dt) {
                f16x8 vf = *(const f16x8*)&v_lds[dt * 16 + r16][ks * 32 + g * 8];
                acc[dt] = __builtin_amdgcn_mfma_f32_16x16x32_f16(pf[ks], vf, acc[dt], 0, 0, 0);
            }
        }
    }

    // epilogue: out[b][s*H + h][d] = acc / l  (l lives in lane q=r16; shfl it)
    #pragma unroll
    for (int i = 0; i < 4; ++i) {
        const float li = __shfl(l, g * 4 + i, 64);
        const float inv = 1.f / li;
        const int sg = qt * 64 + w * 16 + g * 4 + i;
        #pragma unroll
        for (int dt = 0; dt < 8; ++dt)
            out[(((size_t)b * S_LEN + sg) * H_NUM + h) * D_DIM + dt * 16 + r16]
                = acc[dt][i] * inv;
    }
}

extern "C" void kernel_launch(void* const* d_in, const int* in_sizes, int n_in,
                              void* d_out, int out_size, void* d_ws, size_t ws_size,
                              hipStream_t stream) {
    const float* x  = (const float*)d_in[0];
    const float* Wq = (const float*)d_in[1];
    const float* bq = (const float*)d_in[2];
    const float* Wk = (const float*)d_in[3];
    const float* bk = (const float*)d_in[4];
    const float* Wv = (const float*)d_in[5];
    const float* bv = (const float*)d_in[6];
    float* out = (float*)d_out;

    char* ws = (char*)d_ws;
    _Float16* Wb  = (_Float16*)ws;                     // 3*16384 f16 = 96 KB
    _Float16* Qg  = (_Float16*)(ws + 131072);          // 64*2048*128 f16 = 32 MB
    _Float16* Kg  = Qg + (size_t)64 * S_LEN * D_DIM;
    _Float16* Vtg = Kg + (size_t)64 * S_LEN * D_DIM;   // transposed V

    wconv_kernel<<<64, 256, 0, stream>>>(Wq, Wk, Wv, Wb);
    proj_kernel<<<1024, 256, 0, stream>>>(x, bq, bk, bv, Wb, Qg, Kg, Vtg);
    attn_kernel<<<2048, 256, 0, stream>>>(Qg, Kg, Vtg, out);
}